// Round 1
// baseline (533.598 us; speedup 1.0000x reference)
//
#include <hip/hip_runtime.h>
#include <math.h>

#define P_TOT 4096
#define IN_DIM 1024
#define NCAT 328
#define DDIM 24
#define MKEYS 4096
#define HDIM 256
#define CCENT 256
#define KTOP 32

static const size_t o_Y       = 0;
static const size_t o_q       = o_Y + (size_t)P_TOT*NCAT;
static const size_t o_qq      = o_q + (size_t)P_TOT*DDIM;
static const size_t o_KC      = o_qq + P_TOT;
static const size_t o_KF      = o_KC + (size_t)P_TOT*512;
static const size_t o_keynorm = o_KF + (size_t)P_TOT*512;
static const size_t o_centnorm= o_keynorm + MKEYS;
static const size_t o_coef    = o_centnorm + CCENT;
static const size_t o_bcat    = o_coef + 64;
static const size_t o_Wcat    = o_bcat + 384;
static const size_t o_TT      = o_Wcat + (size_t)IN_DIM*NCAT;
static const size_t o_W2      = o_TT + (size_t)512*512;
static const size_t o_vread   = o_W2 + (size_t)512*72;
static const size_t o_Xcat    = o_vread + (size_t)P_TOT*72;
static const size_t o_mem     = o_Xcat + (size_t)P_TOT*512;
static const size_t o_keysT   = o_mem + (size_t)P_TOT*72;
static const size_t o_sel     = o_keysT + (size_t)DDIM*MKEYS;  // ints
static const size_t o_mask    = o_sel + 256;
static const size_t o_count   = o_mask + MKEYS;
static const size_t o_DOT     = o_count + 64;
static const size_t WS_NEED_DOT = o_DOT + (size_t)P_TOT*MKEYS; // floats

__device__ __forceinline__ float gelu_f(float x){
    return 0.5f * x * (1.0f + erff(x * 0.70710678118654752f));
}

#define TWO_PI_F 6.2831853071795864769f
#define STEP_F   0.024543692606170262f   // 2*pi/256

// ---------------- setup kernels ----------------
__global__ void setup_small(const float* __restrict__ fw, const float* __restrict__ b_in,
                            const float* __restrict__ bk, const float* __restrict__ cent,
                            float* __restrict__ coefp, float* __restrict__ bcat,
                            float* __restrict__ centnorm, int* __restrict__ sel,
                            int* __restrict__ count)
{
    int t = threadIdx.x;
    if (t == 0){
        float m = fmaxf(fmaxf(fw[0],fw[1]),fmaxf(fw[2],fw[3]));
        float e0=expf(fw[0]-m), e1=expf(fw[1]-m), e2=expf(fw[2]-m), e3=expf(fw[3]-m);
        float s = e0+e1+e2+e3;
        *coefp = (e0 + e1*0.25f + e2*0.0625f + e3*0.015625f) / s;
        *count = 0;
    }
    if (t < 72) bcat[t] = b_in[t];
    if (t >= 72) bcat[t] = bk[t-72];
    int t2 = t + 256;
    if (t2 < NCAT) bcat[t2] = bk[t2-72];
    if (t < CCENT){
        sel[t] = 0;
        float s = 0.f;
        #pragma unroll
        for (int d=0; d<DDIM; ++d){ float v = cent[t*DDIM+d]; s += v*v; }
        centnorm[t] = s;
    }
}

__global__ void key_setup(const float* __restrict__ keys, float* __restrict__ keynorm,
                          float* __restrict__ keysT)
{
    int m = blockIdx.x*256 + threadIdx.x;
    float s = 0.f;
    #pragma unroll
    for (int d=0; d<DDIM; ++d){ float v = keys[m*DDIM+d]; s += v*v; keysT[(size_t)d*MKEYS + m] = v; }
    keynorm[m] = s;
}

__global__ void build_Wcat(const float* __restrict__ W_in, const float* __restrict__ Wk,
                           float* __restrict__ Wcat)
{
    int idx = blockIdx.x*256 + threadIdx.x;
    if (idx >= IN_DIM*NCAT) return;
    int k = idx / NCAT, n = idx - k*NCAT;
    Wcat[idx] = (n < 72) ? W_in[k*72 + n] : Wk[k*256 + (n-72)];
}

// forward-DFT + entangle folded: TT (512x512).  kf_e[n] = sum_h (a+ib) * e^{-i(theta(nh)-ek[n])}
__global__ void build_TT(const float* __restrict__ ek, float* __restrict__ TT)
{
    int idx = blockIdx.x*256 + threadIdx.x;   // 512*512 total
    int r = idx >> 9, c = idx & 511;
    int n = c & 255, h = r & 255;
    float th = (float)((n*h) & 255) * STEP_F - ek[n];
    float sn, cs; sincosf(th, &sn, &cs);
    float v;
    if (r < 256) v = (c < 256) ? cs : -sn;   // a-rows
    else         v = (c < 256) ? sn : cs;    // b-rows
    TT[idx] = v;
}

// inverse-DFT folded into W_read: W2 (512x72)
__global__ void build_W2(const float* __restrict__ Wr, float* __restrict__ W2)
{
    __shared__ float tab[256];
    int t = threadIdx.x;
    tab[t] = cosf((float)t * STEP_F);
    __syncthreads();
    int idx = blockIdx.x*256 + t;   // 512*72 = 36864 total
    if (idx >= 512*72) return;
    int k = idx / 72, j = idx - k*72;
    int n = k & 255;
    float acc = 0.f;
    for (int h=0; h<256; ++h){
        int x = (n*h) & 255;
        float c = tab[x], s = tab[(x+192) & 255];   // sin(theta)=cos(theta+3pi/2)
        float w1 = Wr[h*72 + j], w2 = Wr[(256+h)*72 + j];
        acc += (k < 256) ? (c*w1 + s*w2) : (c*w2 - s*w1);
    }
    W2[idx] = acc * (1.f/256.f);
}

// ---------------- generic tiled fp32 GEMM ----------------
// C[M,N] = A[M,K] @ op(B) (+bias[n]) (+addm[m,n]);  BT=1 -> B is [N,K]
__global__ __launch_bounds__(256) void gemm_f32(
    const float* __restrict__ A, const float* __restrict__ B,
    float* __restrict__ C, const float* __restrict__ bias,
    const float* __restrict__ addm, int M, int N, int K, int BT)
{
    __shared__ __align__(16) float As[16][68];
    __shared__ __align__(16) float Bs[16][68];
    const int tid = threadIdx.x;
    const int tx = tid & 15, ty = tid >> 4;
    const int m0 = blockIdx.y * 64, n0 = blockIdx.x * 64;
    float acc[4][4] = {};
    for (int k0 = 0; k0 < K; k0 += 16){
        #pragma unroll
        for (int i = 0; i < 4; ++i){
            int f = tid + 256*i;
            int k = f & 15, m = f >> 4;
            int gk = k0 + k;
            As[k][m] = (gk < K) ? A[(size_t)(m0+m)*K + gk] : 0.f;
        }
        if (BT){
            #pragma unroll
            for (int i = 0; i < 4; ++i){
                int f = tid + 256*i;
                int k = f & 15, n = f >> 4;
                int gk = k0 + k, gn = n0 + n;
                float v = 0.f;
                if (gk < K && gn < N) v = B[(size_t)gn*K + gk];
                Bs[k][n] = v;
            }
        } else {
            #pragma unroll
            for (int i = 0; i < 4; ++i){
                int f = tid + 256*i;
                int n = f & 63, k = f >> 6;
                int gk = k0 + k, gn = n0 + n;
                float v = 0.f;
                if (gk < K && gn < N) v = B[(size_t)gk*N + gn];
                Bs[k][n] = v;
            }
        }
        __syncthreads();
        #pragma unroll
        for (int k = 0; k < 16; ++k){
            float4 a4 = *(const float4*)&As[k][ty*4];
            float4 b4 = *(const float4*)&Bs[k][tx*4];
            float a[4] = {a4.x,a4.y,a4.z,a4.w};
            float b[4] = {b4.x,b4.y,b4.z,b4.w};
            #pragma unroll
            for (int i=0;i<4;++i)
                #pragma unroll
                for (int j=0;j<4;++j) acc[i][j] += a[i]*b[j];
        }
        __syncthreads();
    }
    #pragma unroll
    for (int i=0;i<4;++i){
        int m = m0 + ty*4 + i;
        #pragma unroll
        for (int j=0;j<4;++j){
            int n = n0 + tx*4 + j;
            if (n < N){
                float v = acc[i][j];
                if (bias) v += bias[n];
                if (addm) v += addm[(size_t)m*N + n];
                C[(size_t)m*N + n] = v;
            }
        }
    }
}

// ---------------- LN+GELU+ricci+phase over projection ----------------
__global__ __launch_bounds__(256) void post_proj(
    const float* __restrict__ Y, const float* __restrict__ ricci,
    float* __restrict__ q, float* __restrict__ qq, float* __restrict__ KC)
{
    int wave = threadIdx.x >> 6, lane = threadIdx.x & 63;
    int p = blockIdx.x*4 + wave;
    __shared__ float zsh[4][72];
    __shared__ float zbsh[4][24];
    const float* Yr = Y + (size_t)p*NCAT;
    float v1 = Yr[lane];
    float v2 = (lane < 8) ? Yr[64+lane] : 0.f;
    float s = v1 + v2, s2 = v1*v1 + v2*v2;
    #pragma unroll
    for (int off=32; off; off>>=1){ s += __shfl_xor(s,off); s2 += __shfl_xor(s2,off); }
    float mean = s * (1.f/72.f);
    float var  = s2 * (1.f/72.f) - mean*mean;
    float rstd = rsqrtf(var + 1e-5f);
    zsh[wave][lane] = gelu_f((v1-mean)*rstd);
    if (lane < 8) zsh[wave][64+lane] = gelu_f((v2-mean)*rstd);
    __syncthreads();
    if (lane < 24){
        float zb = (zsh[wave][lane*3] + zsh[wave][lane*3+1] + zsh[wave][lane*3+2]) * (1.f/3.f);
        zbsh[wave][lane] = zb;
    }
    __syncthreads();
    float qd = 0.f;
    if (lane < 24){
        #pragma unroll
        for (int e=0;e<24;++e) qd += zbsh[wave][e] * ricci[e*24+lane];
        q[(size_t)p*DDIM + lane] = qd;
    }
    float qs = (lane<24) ? qd*qd : 0.f;
    #pragma unroll
    for (int off=32; off; off>>=1) qs += __shfl_xor(qs,off);
    if (lane == 0) qq[p] = qs;
    // complex key phases -> KC row [cos(256) | sin(256)]
    #pragma unroll
    for (int j=0;j<4;++j){
        int h = lane + 64*j;
        float u = Yr[72+h];
        float ph = TWO_PI_F / (1.f + expf(-u));
        float sn, cs; sincosf(ph, &sn, &cs);
        KC[(size_t)p*512 + h]       = cs;
        KC[(size_t)p*512 + 256 + h] = sn;
    }
}

// ---------------- centroid top-8, global union ----------------
__global__ __launch_bounds__(256) void cent_topk(
    const float* __restrict__ q, const float* __restrict__ qq,
    const float* __restrict__ centroids, const float* __restrict__ centnorm,
    int* __restrict__ sel)
{
    int wave = threadIdx.x >> 6, lane = threadIdx.x & 63;
    int p = blockIdx.x*4 + wave;
    __shared__ float qsh[4][24];
    if (lane < 24) qsh[wave][lane] = q[(size_t)p*DDIM + lane];
    __syncthreads();
    float qv = qq[p];
    float d[4]; int ci[4];
    #pragma unroll
    for (int j=0;j<4;++j){
        int c = lane + 64*j;
        float dot = 0.f;
        #pragma unroll
        for (int e=0;e<24;++e) dot += qsh[wave][e]*centroids[c*24+e];
        d[j] = qv + centnorm[c] - 2.f*dot;
        ci[j] = c;
    }
    for (int k=0;k<8;++k){
        float mv = d[0]; int mi = ci[0];
        #pragma unroll
        for (int j=1;j<4;++j) if (d[j] < mv || (d[j]==mv && ci[j]<mi)){ mv=d[j]; mi=ci[j]; }
        #pragma unroll
        for (int off=32; off; off>>=1){
            float ov = __shfl_xor(mv,off); int oi = __shfl_xor(mi,off);
            if (ov < mv || (ov==mv && oi<mi)){ mv=ov; mi=oi; }
        }
        if ((mi & 63) == lane){
            int j = mi >> 6;
            if (j==0) d[0]=INFINITY; else if (j==1) d[1]=INFINITY;
            else if (j==2) d[2]=INFINITY; else d[3]=INFINITY;
            sel[mi] = 1;
        }
    }
}

__global__ void mask_count(const int* __restrict__ sel, const int* __restrict__ cids,
                           int* __restrict__ maskKey, int* __restrict__ count)
{
    int m = blockIdx.x*256 + threadIdx.x;
    int v = sel[cids[m]];
    maskKey[m] = v;
    int lane = threadIdx.x & 63;
    #pragma unroll
    for (int off=32; off; off>>=1) v += __shfl_xor(v, off);
    if (lane == 0) atomicAdd(count, v);
}

// ---------------- top-32 select + value/holo read ----------------
template<int USE_DOT>
__global__ __launch_bounds__(256) void select_read(
    const float* __restrict__ DOT, const float* __restrict__ keysT,
    const float* __restrict__ q, const float* __restrict__ qq,
    const float* __restrict__ keynorm, const int* __restrict__ maskKey,
    const int* __restrict__ count, const float* __restrict__ coefp,
    const float* __restrict__ values, const float* __restrict__ hr,
    const float* __restrict__ hi, const float* __restrict__ KF,
    float* __restrict__ vread, float* __restrict__ Xcat)
{
    const int p = blockIdx.x;
    const int t = threadIdx.x;
    __shared__ float sd[MKEYS];
    __shared__ float q24[24];
    __shared__ float rv[4]; __shared__ int ri[4];
    __shared__ float sv[KTOP]; __shared__ int sidx[KTOP];
    __shared__ float sw[KTOP];
    __shared__ float ssum_sh;
    bool useAll = (*count) < 32;
    float coef = *coefp;
    float qv = qq[p];
    if (t < 24) q24[t] = q[(size_t)p*DDIM + t];
    __syncthreads();

    if (USE_DOT){
        #pragma unroll
        for (int i=0;i<16;++i){
            int m = t + 256*i;
            float dot = DOT[(size_t)p*MKEYS + m];
            float dd = qv + keynorm[m] - 2.f*dot;
            bool ok = useAll || (maskKey[m] != 0);
            sd[m] = ok ? dd : INFINITY;
        }
    } else {
        float qr[24];
        #pragma unroll
        for (int e=0;e<24;++e) qr[e] = q24[e];
        float acc[16];
        #pragma unroll
        for (int i=0;i<16;++i) acc[i] = 0.f;
        for (int e=0;e<24;++e){
            float qd = qr[e];
            const float* kr = keysT + (size_t)e*MKEYS + t;
            #pragma unroll
            for (int i=0;i<16;++i) acc[i] += qd * kr[256*i];
        }
        #pragma unroll
        for (int i=0;i<16;++i){
            int m = t + 256*i;
            float dd = qv + keynorm[m] - 2.f*acc[i];
            bool ok = useAll || (maskKey[m] != 0);
            sd[m] = ok ? dd : INFINITY;
        }
    }
    __syncthreads();

    float mv = INFINITY; int mi = 0x7fffffff;
    #pragma unroll
    for (int i=0;i<16;++i){
        int m = t + 256*i; float v = sd[m];
        if (v < mv){ mv = v; mi = m; }
    }
    int lane = t & 63, wid = t >> 6;
    for (int k=0;k<KTOP;++k){
        float v = mv; int idx = mi;
        #pragma unroll
        for (int off=32; off; off>>=1){
            float ov = __shfl_xor(v,off); int oi = __shfl_xor(idx,off);
            if (ov < v || (ov==v && oi<idx)){ v=ov; idx=oi; }
        }
        if (lane == 0){ rv[wid] = v; ri[wid] = idx; }
        __syncthreads();
        float gv = rv[0]; int gi = ri[0];
        #pragma unroll
        for (int w=1; w<4; ++w){
            float ov = rv[w]; int oi = ri[w];
            if (ov < gv || (ov==gv && oi<gi)){ gv=ov; gi=oi; }
        }
        if (t == 0){ sv[k] = gv; sidx[k] = gi; }
        if (t == (gi & 255)){
            sd[gi] = INFINITY;
            mv = INFINITY; mi = 0x7fffffff;
            #pragma unroll
            for (int i=0;i<16;++i){ int m = t+256*i; float vv = sd[m]; if (vv < mv){ mv=vv; mi=m; } }
        }
        __syncthreads();
    }

    if (t < KTOP) sw[t] = expf(-coef * (sv[t] - sv[0]));
    __syncthreads();
    if (t == 0){
        float s = 0.f;
        #pragma unroll
        for (int k=0;k<KTOP;++k) s += sw[k];
        ssum_sh = 1.f / s;
    }
    __syncthreads();
    float inv = ssum_sh;

    if (t < 72){
        float a = 0.f;
        for (int k=0;k<KTOP;++k) a += sw[k]*values[(size_t)sidx[k]*72 + t];
        vread[(size_t)p*72 + t] = a * inv;
    }
    {
        int h = t;
        float sr = 0.f, si = 0.f;
        for (int k=0;k<KTOP;++k){
            float w = sw[k];
            size_t off = (size_t)sidx[k]*HDIM + h;
            sr += w*hr[off]; si += w*hi[off];
        }
        sr *= inv; si *= inv;
        float Rk = KF[(size_t)p*512 + h], Ik = KF[(size_t)p*512 + 256 + h];
        Xcat[(size_t)p*512 + h]       = sr*Rk + si*Ik;   // Re(S * conj(kf))
        Xcat[(size_t)p*512 + 256 + h] = si*Rk - sr*Ik;   // Im(S * conj(kf))
    }
}

// ---------------- final LN+GELU, in place on d_out ----------------
__global__ __launch_bounds__(256) void ln_gelu_out(float* __restrict__ O)
{
    int p = blockIdx.x; int t = threadIdx.x;
    float4 v = *(float4*)&O[(size_t)p*IN_DIM + t*4];
    float s  = v.x+v.y+v.z+v.w;
    float s2 = v.x*v.x+v.y*v.y+v.z*v.z+v.w*v.w;
    #pragma unroll
    for (int off=32; off; off>>=1){ s += __shfl_xor(s,off); s2 += __shfl_xor(s2,off); }
    __shared__ float as[4], as2[4];
    int lane = t & 63, w = t >> 6;
    if (lane == 0){ as[w] = s; as2[w] = s2; }
    __syncthreads();
    s = as[0]+as[1]+as[2]+as[3];
    s2 = as2[0]+as2[1]+as2[2]+as2[3];
    float mean = s * (1.f/1024.f);
    float var  = s2 * (1.f/1024.f) - mean*mean;
    float rstd = rsqrtf(var + 1e-5f);
    v.x = gelu_f((v.x-mean)*rstd);
    v.y = gelu_f((v.y-mean)*rstd);
    v.z = gelu_f((v.z-mean)*rstd);
    v.w = gelu_f((v.w-mean)*rstd);
    *(float4*)&O[(size_t)p*IN_DIM + t*4] = v;
}

extern "C" void kernel_launch(void* const* d_in, const int* in_sizes, int n_in,
                              void* d_out, int out_size, void* d_ws, size_t ws_size,
                              hipStream_t stream)
{
    const float* x      = (const float*)d_in[0];
    const float* keys   = (const float*)d_in[1];
    const float* values = (const float*)d_in[2];
    const float* W_in   = (const float*)d_in[3];
    const float* b_in   = (const float*)d_in[4];
    const float* ricci  = (const float*)d_in[5];
    const float* fw     = (const float*)d_in[6];
    const float* cent   = (const float*)d_in[7];
    const float* Wk     = (const float*)d_in[8];
    const float* bk     = (const float*)d_in[9];
    const float* ek     = (const float*)d_in[10];
    const float* hr     = (const float*)d_in[11];
    const float* hi     = (const float*)d_in[12];
    const float* Wr     = (const float*)d_in[13];
    const float* brd    = (const float*)d_in[14];
    const float* W_out  = (const float*)d_in[15];
    const float* b_out  = (const float*)d_in[16];
    const int*   cids   = (const int*)d_in[17];
    float* ws  = (float*)d_ws;
    float* out = (float*)d_out;
    int* sel   = (int*)(ws + o_sel);
    int* mask  = (int*)(ws + o_mask);
    int* count = (int*)(ws + o_count);
    bool useDot = ws_size >= WS_NEED_DOT * sizeof(float);

    setup_small<<<1,256,0,stream>>>(fw, b_in, bk, cent, ws+o_coef, ws+o_bcat, ws+o_centnorm, sel, count);
    key_setup<<<16,256,0,stream>>>(keys, ws+o_keynorm, ws+o_keysT);
    build_Wcat<<<(IN_DIM*NCAT+255)/256,256,0,stream>>>(W_in, Wk, ws+o_Wcat);
    build_TT<<<1024,256,0,stream>>>(ek, ws+o_TT);
    build_W2<<<144,256,0,stream>>>(Wr, ws+o_W2);

    // Y = x @ [W_in|Wk] + [b_in|bk]
    gemm_f32<<<dim3(6,64),256,0,stream>>>(x, ws+o_Wcat, ws+o_Y, ws+o_bcat, nullptr, P_TOT, NCAT, IN_DIM, 0);
    post_proj<<<1024,256,0,stream>>>(ws+o_Y, ricci, ws+o_q, ws+o_qq, ws+o_KC);
    // KF = KC @ TT  (forward FFT + entangle)
    gemm_f32<<<dim3(8,64),256,0,stream>>>(ws+o_KC, ws+o_TT, ws+o_KF, nullptr, nullptr, P_TOT, 512, 512, 0);
    if (useDot)
        gemm_f32<<<dim3(64,64),256,0,stream>>>(ws+o_q, keys, ws+o_DOT, nullptr, nullptr, P_TOT, MKEYS, DDIM, 1);
    cent_topk<<<1024,256,0,stream>>>(ws+o_q, ws+o_qq, cent, ws+o_centnorm, sel);
    mask_count<<<16,256,0,stream>>>(sel, cids, mask, count);
    if (useDot)
        select_read<1><<<P_TOT,256,0,stream>>>(ws+o_DOT, ws+o_keysT, ws+o_q, ws+o_qq, ws+o_keynorm,
                                               mask, count, ws+o_coef, values, hr, hi, ws+o_KF,
                                               ws+o_vread, ws+o_Xcat);
    else
        select_read<0><<<P_TOT,256,0,stream>>>(ws+o_DOT, ws+o_keysT, ws+o_q, ws+o_qq, ws+o_keynorm,
                                               mask, count, ws+o_coef, values, hr, hi, ws+o_KF,
                                               ws+o_vread, ws+o_Xcat);
    // mem = Xcat @ W2 + b_read + vread   (inverse FFT folded into W2)
    gemm_f32<<<dim3(2,64),256,0,stream>>>(ws+o_Xcat, ws+o_W2, ws+o_mem, brd, ws+o_vread, P_TOT, 72, 512, 0);
    // out = mem @ W_out + b_out, then LN+GELU in place
    gemm_f32<<<dim3(16,64),256,0,stream>>>(ws+o_mem, W_out, out, b_out, nullptr, P_TOT, IN_DIM, 72, 0);
    ln_gelu_out<<<P_TOT,256,0,stream>>>(out);
}